// Round 8
// baseline (903024.316 us; speedup 1.0000x reference)
//
#include <hip/hip_runtime.h>
#include <hip/hip_bf16.h>
#include <hip/hip_cooperative_groups.h>

#define EMBED 128
#define HID   256
#define BB    256   // batch
#define TT    512   // time
#define G4    1024  // 4*HID

typedef __attribute__((ext_vector_type(8))) short short8;
typedef __attribute__((ext_vector_type(4))) float f32x4;

// ---- workspace layout (bytes) ----
// WUp   : [dir][jg][gate][jc:32][k:384] bf16
// bp    : [dir][jg][gate][jc:32] f32
// xhat  : [B][T][128] bf16
// hbuf  : [dir][parity][B][HID] bf16
// hfinal: [dir][B][HID] f32
// flags : per-wave step flags [dir][jg][bg][wid], 256B apart (one L2 line each,
//         so differently-scoped groups NEVER share a cache line)
// xcdtab: [bid] publish (0x100|xcd), 64B apart (always device-scope, uniform)
#define OFF_WUP   0
#define SZ_WUP    (2*8*4*32*384*2)           // 1,572,864
#define OFF_BP    (OFF_WUP + SZ_WUP)
#define SZ_BP     (2*8*4*32*4)               // 4,096
#define OFF_XHAT  (OFF_BP + SZ_BP)
#define SZ_XHAT   ((size_t)BB*TT*EMBED*2)    // 33,554,432
#define OFF_HBUF  (OFF_XHAT + SZ_XHAT)
#define SZ_HBUF   (2*2*BB*HID*2)             // 524,288
#define OFF_HFIN  (OFF_HBUF + SZ_HBUF)
#define SZ_HFIN   (2*BB*HID*4)               // 524,288
#define OFF_FLAGS (OFF_HFIN + SZ_HFIN)
#define SZ_FLAGS  (2*8*8*4*64*4)             // 131,072 (512 wave-flags x 256B)
#define OFF_XCD   (OFF_FLAGS + SZ_FLAGS)
#define SZ_XCD    (128*16*4)                 // 8,192

#define SPIN_GUARD (1 << 14)     // legit waits < 10us; guard trips at ~7ms -> fast fail
#define HS_GUARD   (1 << 20)     // one-time handshake

__global__ void pack_kernel(const float* __restrict__ Wf, const float* __restrict__ Uf,
                            const float* __restrict__ bf,
                            const float* __restrict__ Wb, const float* __restrict__ Ub,
                            const float* __restrict__ bb,
                            __hip_bfloat16* __restrict__ WUp, float* __restrict__ bp) {
    int flat = blockIdx.x * 256 + threadIdx.x;          // [0, 2*8*4*32*384)
    int k = flat % 384;
    int rest = flat / 384;                              // [dir][jg][gate][jc]
    int jc   = rest & 31;
    int gate = (rest >> 5) & 3;
    int jg   = (rest >> 7) & 7;
    int dir  = rest >> 10;
    int J = gate * 256 + jg * 32 + jc;
    const float* W = dir ? Wb : Wf;
    const float* U = dir ? Ub : Uf;
    float v = (k < 128) ? W[(size_t)k * G4 + J] : U[(size_t)(k - 128) * G4 + J];
    WUp[flat] = __float2bfloat16(v);
    if (k == 0) {
        const float* bias = dir ? bb : bf;
        bp[rest] = bias[J];
    }
}

__global__ void gather_kernel(const int* __restrict__ inputs, const float* __restrict__ embed,
                              __hip_bfloat16* __restrict__ xhat) {
    int row = blockIdx.x * 2 + (threadIdx.x >> 7);      // [0, B*T)
    int col = threadIdx.x & 127;
    int tok = inputs[row];
    xhat[(size_t)row * EMBED + col] = __float2bfloat16(embed[(size_t)tok * EMBED + col]);
}

// Writeback + invalidate the local XCD's L2 (64 blocks round-robin all 8 XCDs).
// Kills stale dirty/clean lines from previous replays so sc0 traffic starts
// from a coherent MALL image.
__global__ void preclean_kernel() {
    if (threadIdx.x == 0) {
        asm volatile("buffer_wbl2 sc1\n\t"
                     "s_waitcnt vmcnt(0)\n\t"
                     "buffer_inv sc1\n\t"
                     "s_waitcnt vmcnt(0)" ::: "memory");
    }
}

// Zero flags + xcdtab through the device-scope bypass path.
__global__ void init_flags_kernel(int* __restrict__ p) {
    int i = blockIdx.x * 256 + threadIdx.x;             // 34816 dwords
    int* q = p + i;
    unsigned z = 0;
    asm volatile("global_store_dword %0, %1, off sc0 sc1" :: "v"(q), "v"(z) : "memory");
}

__device__ __forceinline__ float sigf(float x) { return 1.f / (1.f + __expf(-x)); }
__device__ __forceinline__ float ftanh(float x) { return 2.f / (1.f + __expf(-2.f * x)) - 1.f; }

// FAST = all 8 jg-peer blocks of this (dir,bg) group share one XCD -> h and
// flag traffic at L2 scope (sc0, plain loads/stores; R5 proved sc0 loads are
// never served stale from L1). Otherwise device scope (sc0 sc1) = R3 exactly.
template<bool FAST>
__device__ __forceinline__ void lstm_loop(
        int dir, int jg, int bg, int wid, int lane,
        const int* __restrict__ inputs, const short* __restrict__ xrow,
        short* __restrict__ hbufs, int* __restrict__ flags,
        const short8 (*wfrag)[12], const float* bias,
        float* c_st, float* h_st, int brow0, int mrow0, int l15, int lhi, int jch) {

    const int rh = wid >> 1;                 // row half of this wave
    int* myflag = flags + ((((dir * 8 + jg) * 8 + bg) * 4) + wid) * 64;
    const int l16 = lane & 15;
    int* pollp = flags + ((((dir * 8 + (l16 >> 1)) * 8 + bg) * 4) + (2 * rh + (l16 & 1))) * 64;

    // x fragments + masks for step 0 (normal cached loads)
    short8 xf[4];
    int mk_cur[4], mk_nxt[4];
    {
        const int t0 = dir ? (TT - 1) : 0;
#pragma unroll
        for (int kt = 0; kt < 4; ++kt)
            xf[kt] = *(const short8*)(xrow + (size_t)t0 * EMBED + kt * 32 + 8 * lhi);
#pragma unroll
        for (int r = 0; r < 4; ++r)
            mk_cur[r] = inputs[(size_t)(brow0 + r) * TT + t0];
    }

    for (int s = 0; s < TT; ++s) {
        // ---- x-part of z (xf prefetched); bias folded into acc init ----
        f32x4 acc[4];
#pragma unroll
        for (int g = 0; g < 4; ++g) {
            acc[g][0] = bias[g]; acc[g][1] = bias[g]; acc[g][2] = bias[g]; acc[g][3] = bias[g];
        }
#pragma unroll
        for (int kt = 0; kt < 4; ++kt)
#pragma unroll
            for (int g = 0; g < 4; ++g)
                acc[g] = __builtin_amdgcn_mfma_f32_16x16x32_bf16(xf[kt], wfrag[g][kt], acc[g], 0, 0, 0);

        const int tn = dir ? (TT - 2 - s) : (s + 1);   // next t (valid when s+1<TT)

        if (s != 0) {
            // ---- wait for h(s): poll 16 producer-wave flags ----
            {
                int fv, guard = 0;
                if constexpr (FAST) {
                    do {
                        asm volatile("global_load_dword %0, %1, off sc0\n\t"
                                     "s_waitcnt vmcnt(0)"
                                     : "=v"(fv) : "v"(pollp) : "memory");
                        if (++guard > SPIN_GUARD) break;   // pathological -> fast fail
                    } while (__any(fv < s));
                } else {
                    do {
                        asm volatile("global_load_dword %0, %1, off sc0 sc1\n\t"
                                     "s_waitcnt vmcnt(0)"
                                     : "=v"(fv) : "v"(pollp) : "memory");
                        if (++guard > SPIN_GUARD) break;
                    } while (__any(fv < s));
                }
            }

            // ---- h fragments: L2-scope on fast path ----
            short8 hf[8];
            const short* hbase = hbufs + (size_t)(dir * 2 + (s & 1)) * BB * HID
                               + (size_t)(mrow0 + l15) * HID + 8 * lhi;
            if constexpr (FAST) {
                asm volatile(
                    "global_load_dwordx4 %0, %8, off sc0\n\t"
                    "global_load_dwordx4 %1, %8, off offset:64 sc0\n\t"
                    "global_load_dwordx4 %2, %8, off offset:128 sc0\n\t"
                    "global_load_dwordx4 %3, %8, off offset:192 sc0\n\t"
                    "global_load_dwordx4 %4, %8, off offset:256 sc0\n\t"
                    "global_load_dwordx4 %5, %8, off offset:320 sc0\n\t"
                    "global_load_dwordx4 %6, %8, off offset:384 sc0\n\t"
                    "global_load_dwordx4 %7, %8, off offset:448 sc0\n\t"
                    "s_waitcnt vmcnt(0)"
                    : "=&v"(hf[0]), "=&v"(hf[1]), "=&v"(hf[2]), "=&v"(hf[3]),
                      "=&v"(hf[4]), "=&v"(hf[5]), "=&v"(hf[6]), "=&v"(hf[7])
                    : "v"(hbase) : "memory");
            } else {
                asm volatile(
                    "global_load_dwordx4 %0, %8, off sc0 sc1\n\t"
                    "global_load_dwordx4 %1, %8, off offset:64 sc0 sc1\n\t"
                    "global_load_dwordx4 %2, %8, off offset:128 sc0 sc1\n\t"
                    "global_load_dwordx4 %3, %8, off offset:192 sc0 sc1\n\t"
                    "global_load_dwordx4 %4, %8, off offset:256 sc0 sc1\n\t"
                    "global_load_dwordx4 %5, %8, off offset:320 sc0 sc1\n\t"
                    "global_load_dwordx4 %6, %8, off offset:384 sc0 sc1\n\t"
                    "global_load_dwordx4 %7, %8, off offset:448 sc0 sc1\n\t"
                    "s_waitcnt vmcnt(0)"
                    : "=&v"(hf[0]), "=&v"(hf[1]), "=&v"(hf[2]), "=&v"(hf[3]),
                      "=&v"(hf[4]), "=&v"(hf[5]), "=&v"(hf[6]), "=&v"(hf[7])
                    : "v"(hbase) : "memory");
            }
            __builtin_amdgcn_sched_barrier(0);

            // ---- prefetch x + next-step masks (hide under MFMA+gates) ----
            if (s + 1 < TT) {
#pragma unroll
                for (int kt = 0; kt < 4; ++kt)
                    xf[kt] = *(const short8*)(xrow + (size_t)tn * EMBED + kt * 32 + 8 * lhi);
#pragma unroll
                for (int r = 0; r < 4; ++r)
                    mk_nxt[r] = inputs[(size_t)(brow0 + r) * TT + tn];
            }

            // ---- h-part MFMAs ----
#pragma unroll
            for (int kt = 0; kt < 8; ++kt)
#pragma unroll
                for (int g = 0; g < 4; ++g)
                    acc[g] = __builtin_amdgcn_mfma_f32_16x16x32_bf16(hf[kt], wfrag[g][kt + 4], acc[g], 0, 0, 0);
        } else {
            // s==0: h=0; just prefetch next x + masks
#pragma unroll
            for (int kt = 0; kt < 4; ++kt)
                xf[kt] = *(const short8*)(xrow + (size_t)tn * EMBED + kt * 32 + 8 * lhi);
#pragma unroll
            for (int r = 0; r < 4; ++r)
                mk_nxt[r] = inputs[(size_t)(brow0 + r) * TT + tn];
        }

        // ---- gates (wave-local) ----
        unsigned hv16[4];
#pragma unroll
        for (int r = 0; r < 4; ++r) {
            float zi = acc[0][r];
            float zf = acc[1][r];
            float zg = acc[2][r];
            float zo = acc[3][r];
            float cn = sigf(zf) * c_st[r] + sigf(zi) * ftanh(zg);
            float hn = sigf(zo) * ftanh(cn);
            if (mk_cur[r] > 0) { c_st[r] = cn; h_st[r] = hn; }
            __hip_bfloat16 hbf = __float2bfloat16(h_st[r]);
            hv16[r] = (unsigned)(*(unsigned short*)&hbf);
        }
#pragma unroll
        for (int r = 0; r < 4; ++r) mk_cur[r] = mk_nxt[r];

        // ---- publish h(s+1): stores + ack, then per-wave flag (no __syncthreads) ----
        {
            const short* sb = hbufs + (size_t)(dir * 2 + ((s + 1) & 1)) * BB * HID
                            + (size_t)brow0 * HID + jg * 32 + jch * 16 + l15;
            if constexpr (FAST) {
                asm volatile(
                    "global_store_short %4, %0, off sc0\n\t"
                    "global_store_short %4, %1, off offset:512 sc0\n\t"
                    "global_store_short %4, %2, off offset:1024 sc0\n\t"
                    "global_store_short %4, %3, off offset:1536 sc0\n\t"
                    "s_waitcnt vmcnt(0)"
                    :: "v"(hv16[0]), "v"(hv16[1]), "v"(hv16[2]), "v"(hv16[3]), "v"(sb)
                    : "memory");
                if (lane == 0) {
                    int val = s + 1;
                    asm volatile("global_store_dword %0, %1, off sc0"
                                 :: "v"(myflag), "v"(val) : "memory");
                }
            } else {
                asm volatile(
                    "global_store_short %4, %0, off sc0 sc1\n\t"
                    "global_store_short %4, %1, off offset:512 sc0 sc1\n\t"
                    "global_store_short %4, %2, off offset:1024 sc0 sc1\n\t"
                    "global_store_short %4, %3, off offset:1536 sc0 sc1\n\t"
                    "s_waitcnt vmcnt(0)"
                    :: "v"(hv16[0]), "v"(hv16[1]), "v"(hv16[2]), "v"(hv16[3]), "v"(sb)
                    : "memory");
                if (lane == 0) {
                    int val = s + 1;
                    asm volatile("global_store_dword %0, %1, off sc0 sc1"
                                 :: "v"(myflag), "v"(val) : "memory");
                }
            }
        }
    }
}

__launch_bounds__(256, 1)
__global__ void lstm_kernel(const int* __restrict__ inputs,
                            const __hip_bfloat16* __restrict__ xhat,
                            const __hip_bfloat16* __restrict__ WUp,
                            const float* __restrict__ bp,
                            __hip_bfloat16* __restrict__ hbuf,
                            float* __restrict__ hfinal,
                            int* __restrict__ flags,
                            int* __restrict__ xcdtab) {
    const int bid = blockIdx.x;          // bid = jg*16 + dir*8 + bg  (jg-peers share bid%8)
    const int jg  = bid >> 4;
    const int dir = (bid >> 3) & 1;
    const int bg  = bid & 7;
    const int tid = threadIdx.x;
    const int wid = tid >> 6;            // wave 0..3
    const int lane = tid & 63;
    const int l15 = lane & 15, lhi = lane >> 4;
    const int jch = wid & 1;             // output col half within jg's 32
    const int mrow0 = bg * 32 + (wid >> 1) * 16;
    const int brow0 = mrow0 + 4 * lhi;

    // ---- preload weights: 4 gates x 12 k-tiles ----
    short8 wfrag[4][12];
    const short* wu = (const short*)WUp + (size_t)(dir * 8 + jg) * 4 * 32 * 384;
#pragma unroll
    for (int g = 0; g < 4; ++g)
#pragma unroll
        for (int kt = 0; kt < 12; ++kt)
            wfrag[g][kt] = *(const short8*)(wu + (size_t)(g * 32 + jch * 16 + l15) * 384 + kt * 32 + 8 * lhi);

    float bias[4];
#pragma unroll
    for (int g = 0; g < 4; ++g)
        bias[g] = bp[((dir * 8 + jg) * 4 + g) * 32 + jch * 16 + l15];

    // ---- XCD co-residency handshake (device scope, once) ----
    int myxcd;
    asm volatile("s_getreg_b32 %0, hwreg(HW_REG_XCC_ID)" : "=s"(myxcd));
    if (tid == 0) {
        int* mp = xcdtab + bid * 16;
        int pv = 0x100 | myxcd;
        asm volatile("global_store_dword %0, %1, off sc0 sc1" :: "v"(mp), "v"(pv) : "memory");
    }
    int fast;
    {
        const int l8 = lane & 7;
        int* pp = xcdtab + ((l8 * 16) + dir * 8 + bg) * 16;   // peer jg=l8 of my group
        int e, guard = 0;
        do {
            asm volatile("global_load_dword %0, %1, off sc0 sc1\n\t"
                         "s_waitcnt vmcnt(0)"
                         : "=v"(e) : "v"(pp) : "memory");
            if (++guard > HS_GUARD) break;                    // e stays 0 -> slow path
        } while (__any(e == 0));
        fast = (__all(e == (0x100 | myxcd))) ? 1 : 0;
    }

    float c_st[4] = {0, 0, 0, 0};
    float h_st[4] = {0, 0, 0, 0};
    const short* xrow = (const short*)xhat + (size_t)(mrow0 + l15) * TT * EMBED;
    short* hbufs = (short*)hbuf;

    if (fast)
        lstm_loop<true>(dir, jg, bg, wid, lane, inputs, xrow, hbufs, flags,
                        wfrag, bias, c_st, h_st, brow0, mrow0, l15, lhi, jch);
    else
        lstm_loop<false>(dir, jg, bg, wid, lane, inputs, xrow, hbufs, flags,
                         wfrag, bias, c_st, h_st, brow0, mrow0, l15, lhi, jch);

#pragma unroll
    for (int r = 0; r < 4; ++r)
        hfinal[((size_t)dir * BB + brow0 + r) * HID + jg * 32 + jch * 16 + l15] = h_st[r];
}

__global__ void epilogue_kernel(const int* __restrict__ input_end,
                                const float* __restrict__ hfinal,
                                const float* __restrict__ cls_W, const float* __restrict__ cls_b,
                                const float* __restrict__ ent_W, const float* __restrict__ ent_b,
                                float* __restrict__ out) {
    int b = blockIdx.x;
    int lane = threadIdx.x;   // 64 threads
    int ie = input_end[b];
    float pe0 = 0, pe1 = 0, pe2 = 0, pc = 0;
    for (int k = lane; k < 2 * HID; k += 64) {
        float bv, se;
        if (k < HID) {
            bv = hfinal[(size_t)b * HID + k];
            se = hfinal[(size_t)ie * HID + k];
        } else {
            bv = hfinal[(size_t)(BB + b) * HID + (k - HID)];
            se = hfinal[(size_t)(BB + ie) * HID + (k - HID)];
        }
        pe0 += bv * ent_W[k * 3 + 0];
        pe1 += bv * ent_W[k * 3 + 1];
        pe2 += bv * ent_W[k * 3 + 2];
        pc  += se * cls_W[k];
    }
    for (int off = 32; off; off >>= 1) {
        pe0 += __shfl_down(pe0, off);
        pe1 += __shfl_down(pe1, off);
        pe2 += __shfl_down(pe2, off);
        pc  += __shfl_down(pc, off);
    }
    if (lane == 0) {
        float l0 = pe0 + ent_b[0], l1 = pe1 + ent_b[1], l2 = pe2 + ent_b[2];
        float m = fmaxf(l0, fmaxf(l1, l2));
        float e0 = __expf(l0 - m), e1 = __expf(l1 - m), e2 = __expf(l2 - m);
        float ssum = e0 + e1 + e2;
        out[256 + b * 3 + 0] = e0 / ssum;
        out[256 + b * 3 + 1] = e1 / ssum;
        out[256 + b * 3 + 2] = e2 / ssum;
        float cl = pc + cls_b[0];
        out[b] = 1.f / (1.f + __expf(-cl));
    }
}

extern "C" void kernel_launch(void* const* d_in, const int* in_sizes, int n_in,
                              void* d_out, int out_size, void* d_ws, size_t ws_size,
                              hipStream_t stream) {
    const int*   inputs    = (const int*)d_in[0];
    const int*   input_end = (const int*)d_in[1];
    const float* embed     = (const float*)d_in[2];
    const float* Wf        = (const float*)d_in[3];
    const float* Uf        = (const float*)d_in[4];
    const float* bf        = (const float*)d_in[5];
    const float* Wb        = (const float*)d_in[6];
    const float* Ub        = (const float*)d_in[7];
    const float* bb        = (const float*)d_in[8];
    const float* cls_W     = (const float*)d_in[9];
    const float* cls_b     = (const float*)d_in[10];
    const float* ent_W     = (const float*)d_in[11];
    const float* ent_b     = (const float*)d_in[12];
    float* out = (float*)d_out;

    char* ws = (char*)d_ws;
    __hip_bfloat16* WUp    = (__hip_bfloat16*)(ws + OFF_WUP);
    float*          bp     = (float*)(ws + OFF_BP);
    __hip_bfloat16* xhat   = (__hip_bfloat16*)(ws + OFF_XHAT);
    __hip_bfloat16* hbuf   = (__hip_bfloat16*)(ws + OFF_HBUF);
    float*          hfinal = (float*)(ws + OFF_HFIN);
    int*            flags  = (int*)(ws + OFF_FLAGS);
    int*            xcdtab = (int*)(ws + OFF_XCD);

    // 1) writeback+invalidate every XCD L2 (stale-line hygiene for sc0 traffic)
    preclean_kernel<<<64, 64, 0, stream>>>();
    // 2) zero flags + xcdtab (contiguous, 139264 B = 34816 dwords) at MALL
    init_flags_kernel<<<136, 256, 0, stream>>>(flags);
    pack_kernel<<<3072, 256, 0, stream>>>(Wf, Uf, bf, Wb, Ub, bb, WUp, bp);
    gather_kernel<<<BB * TT / 2, 256, 0, stream>>>(inputs, embed, xhat);

    void* args[] = {(void*)&inputs, (void*)&xhat, (void*)&WUp, (void*)&bp,
                    (void*)&hbuf, (void*)&hfinal, (void*)&flags, (void*)&xcdtab};
    hipLaunchCooperativeKernel((void*)lstm_kernel, dim3(128), dim3(256), args, 0, stream);

    epilogue_kernel<<<BB, 64, 0, stream>>>(input_end, hfinal, cls_W, cls_b, ent_W, ent_b, out);
}

// Round 9
// 1148.380 us; speedup vs baseline: 786.3461x; 786.3461x over previous
//
#include <hip/hip_runtime.h>
#include <hip/hip_bf16.h>
#include <hip/hip_cooperative_groups.h>

#define EMBED 128
#define HID   256
#define BB    256   // batch
#define TT    512   // time
#define G4    1024  // 4*HID

typedef __attribute__((ext_vector_type(8))) short short8;
typedef __attribute__((ext_vector_type(4))) float f32x4;

// ---- workspace layout (bytes) ----
// WUp   : [dir][jg][gate][jc:32][k:384] bf16
// bp    : [dir][jg][gate][jc:32] f32
// xhat  : [B][T][128] bf16
// hbuf  : [dir][parity][B][HID] bf16
// hfinal: [dir][B][HID] f32
// flags : per-wave step flags [dir][jg][bg][wid], 256B apart
// xcdtab: [bid] publish (0x100|xcd), 64B apart (device-scope, uniform)
#define OFF_WUP   0
#define SZ_WUP    (2*8*4*32*384*2)           // 1,572,864
#define OFF_BP    (OFF_WUP + SZ_WUP)
#define SZ_BP     (2*8*4*32*4)               // 4,096
#define OFF_XHAT  (OFF_BP + SZ_BP)
#define SZ_XHAT   ((size_t)BB*TT*EMBED*2)    // 33,554,432
#define OFF_HBUF  (OFF_XHAT + SZ_XHAT)
#define SZ_HBUF   (2*2*BB*HID*2)             // 524,288
#define OFF_HFIN  (OFF_HBUF + SZ_HBUF)
#define SZ_HFIN   (2*BB*HID*4)               // 524,288
#define OFF_FLAGS (OFF_HFIN + SZ_HFIN)
#define SZ_FLAGS  (2*8*8*4*64*4)             // 131,072 (512 wave-flags x 256B)
#define OFF_XCD   (OFF_FLAGS + SZ_FLAGS)
#define SZ_XCD    (128*16*4)                 // 8,192

#define SPIN_GUARD (1 << 14)     // legit waits < 10us; trips ~ms scale -> fast fail
#define HS_GUARD   (1 << 20)     // one-time handshake

__global__ void pack_kernel(const float* __restrict__ Wf, const float* __restrict__ Uf,
                            const float* __restrict__ bf,
                            const float* __restrict__ Wb, const float* __restrict__ Ub,
                            const float* __restrict__ bb,
                            __hip_bfloat16* __restrict__ WUp, float* __restrict__ bp) {
    int flat = blockIdx.x * 256 + threadIdx.x;          // [0, 2*8*4*32*384)
    int k = flat % 384;
    int rest = flat / 384;                              // [dir][jg][gate][jc]
    int jc   = rest & 31;
    int gate = (rest >> 5) & 3;
    int jg   = (rest >> 7) & 7;
    int dir  = rest >> 10;
    int J = gate * 256 + jg * 32 + jc;
    const float* W = dir ? Wb : Wf;
    const float* U = dir ? Ub : Uf;
    float v = (k < 128) ? W[(size_t)k * G4 + J] : U[(size_t)(k - 128) * G4 + J];
    WUp[flat] = __float2bfloat16(v);
    if (k == 0) {
        const float* bias = dir ? bb : bf;
        bp[rest] = bias[J];
    }
}

__global__ void gather_kernel(const int* __restrict__ inputs, const float* __restrict__ embed,
                              __hip_bfloat16* __restrict__ xhat) {
    int row = blockIdx.x * 2 + (threadIdx.x >> 7);      // [0, B*T)
    int col = threadIdx.x & 127;
    int tok = inputs[row];
    xhat[(size_t)row * EMBED + col] = __float2bfloat16(embed[(size_t)tok * EMBED + col]);
}

// Writeback + invalidate the local XCD's L2 (64 blocks round-robin all 8 XCDs).
__global__ void preclean_kernel() {
    if (threadIdx.x == 0) {
        asm volatile("buffer_wbl2 sc1\n\t"
                     "s_waitcnt vmcnt(0)\n\t"
                     "buffer_inv sc1\n\t"
                     "s_waitcnt vmcnt(0)" ::: "memory");
    }
}

// Zero flags + xcdtab through the device-scope bypass path.
__global__ void init_flags_kernel(int* __restrict__ p) {
    int i = blockIdx.x * 256 + threadIdx.x;             // 34816 dwords
    int* q = p + i;
    unsigned z = 0;
    asm volatile("global_store_dword %0, %1, off sc0 sc1" :: "v"(q), "v"(z) : "memory");
}

__device__ __forceinline__ float sigf(float x) { return 1.f / (1.f + __expf(-x)); }
__device__ __forceinline__ float ftanh(float x) { return 2.f / (1.f + __expf(-2.f * x)) - 1.f; }

// FAST = all 8 jg-peer blocks of this (dir,bg) group share one XCD.
// Empirical gfx950 cache-bit model (R3/R5/R6/R7/R8):
//   sc0 sc1 load  -> MALL, always fresh (~900cy)      [slow path]
//   sc0 load      -> may hit stale L1 forever         [NEVER use for polls]
//   sc1 load      -> bypass L1, may hit local L2      [fast path: polls + h]
//   sc0 store     -> write-through L1 into local L2   [fast path: h + flags]
template<bool FAST>
__device__ __forceinline__ void lstm_loop(
        int dir, int jg, int bg, int wid, int lane,
        const int* __restrict__ inputs, const short* __restrict__ xrow,
        short* __restrict__ hbufs, int* __restrict__ flags,
        const short8 (*wfrag)[12], const float* bias,
        float* c_st, float* h_st, int brow0, int mrow0, int l15, int lhi, int jch) {

    const int rh = wid >> 1;                 // row half of this wave
    int* myflag = flags + ((((dir * 8 + jg) * 8 + bg) * 4) + wid) * 64;
    const int l16 = lane & 15;
    int* pollp = flags + ((((dir * 8 + (l16 >> 1)) * 8 + bg) * 4) + (2 * rh + (l16 & 1))) * 64;

    // x fragments + masks for step 0 (normal cached loads)
    short8 xf[4];
    int mk_cur[4], mk_nxt[4];
    {
        const int t0 = dir ? (TT - 1) : 0;
#pragma unroll
        for (int kt = 0; kt < 4; ++kt)
            xf[kt] = *(const short8*)(xrow + (size_t)t0 * EMBED + kt * 32 + 8 * lhi);
#pragma unroll
        for (int r = 0; r < 4; ++r)
            mk_cur[r] = inputs[(size_t)(brow0 + r) * TT + t0];
    }

    for (int s = 0; s < TT; ++s) {
        // ---- x-part of z (xf prefetched); bias folded into acc init ----
        f32x4 acc[4];
#pragma unroll
        for (int g = 0; g < 4; ++g) {
            acc[g][0] = bias[g]; acc[g][1] = bias[g]; acc[g][2] = bias[g]; acc[g][3] = bias[g];
        }
#pragma unroll
        for (int kt = 0; kt < 4; ++kt)
#pragma unroll
            for (int g = 0; g < 4; ++g)
                acc[g] = __builtin_amdgcn_mfma_f32_16x16x32_bf16(xf[kt], wfrag[g][kt], acc[g], 0, 0, 0);

        const int tn = dir ? (TT - 2 - s) : (s + 1);   // next t (valid when s+1<TT)

        if (s != 0) {
            // ---- wait for h(s): poll 16 producer-wave flags ----
            {
                int fv, guard = 0;
                if constexpr (FAST) {
                    do {
                        asm volatile("global_load_dword %0, %1, off sc1\n\t"
                                     "s_waitcnt vmcnt(0)"
                                     : "=v"(fv) : "v"(pollp) : "memory");
                        if (++guard > SPIN_GUARD) break;   // pathological -> fast fail
                    } while (__any(fv < s));
                } else {
                    do {
                        asm volatile("global_load_dword %0, %1, off sc0 sc1\n\t"
                                     "s_waitcnt vmcnt(0)"
                                     : "=v"(fv) : "v"(pollp) : "memory");
                        if (++guard > SPIN_GUARD) break;
                    } while (__any(fv < s));
                }
            }

            // ---- h fragments: sc1 = L1-bypass, local-L2 hit on fast path ----
            short8 hf[8];
            const short* hbase = hbufs + (size_t)(dir * 2 + (s & 1)) * BB * HID
                               + (size_t)(mrow0 + l15) * HID + 8 * lhi;
            if constexpr (FAST) {
                asm volatile(
                    "global_load_dwordx4 %0, %8, off sc1\n\t"
                    "global_load_dwordx4 %1, %8, off offset:64 sc1\n\t"
                    "global_load_dwordx4 %2, %8, off offset:128 sc1\n\t"
                    "global_load_dwordx4 %3, %8, off offset:192 sc1\n\t"
                    "global_load_dwordx4 %4, %8, off offset:256 sc1\n\t"
                    "global_load_dwordx4 %5, %8, off offset:320 sc1\n\t"
                    "global_load_dwordx4 %6, %8, off offset:384 sc1\n\t"
                    "global_load_dwordx4 %7, %8, off offset:448 sc1\n\t"
                    "s_waitcnt vmcnt(0)"
                    : "=&v"(hf[0]), "=&v"(hf[1]), "=&v"(hf[2]), "=&v"(hf[3]),
                      "=&v"(hf[4]), "=&v"(hf[5]), "=&v"(hf[6]), "=&v"(hf[7])
                    : "v"(hbase) : "memory");
            } else {
                asm volatile(
                    "global_load_dwordx4 %0, %8, off sc0 sc1\n\t"
                    "global_load_dwordx4 %1, %8, off offset:64 sc0 sc1\n\t"
                    "global_load_dwordx4 %2, %8, off offset:128 sc0 sc1\n\t"
                    "global_load_dwordx4 %3, %8, off offset:192 sc0 sc1\n\t"
                    "global_load_dwordx4 %4, %8, off offset:256 sc0 sc1\n\t"
                    "global_load_dwordx4 %5, %8, off offset:320 sc0 sc1\n\t"
                    "global_load_dwordx4 %6, %8, off offset:384 sc0 sc1\n\t"
                    "global_load_dwordx4 %7, %8, off offset:448 sc0 sc1\n\t"
                    "s_waitcnt vmcnt(0)"
                    : "=&v"(hf[0]), "=&v"(hf[1]), "=&v"(hf[2]), "=&v"(hf[3]),
                      "=&v"(hf[4]), "=&v"(hf[5]), "=&v"(hf[6]), "=&v"(hf[7])
                    : "v"(hbase) : "memory");
            }
            __builtin_amdgcn_sched_barrier(0);

            // ---- prefetch x + next-step masks (hide under MFMA+gates) ----
            if (s + 1 < TT) {
#pragma unroll
                for (int kt = 0; kt < 4; ++kt)
                    xf[kt] = *(const short8*)(xrow + (size_t)tn * EMBED + kt * 32 + 8 * lhi);
#pragma unroll
                for (int r = 0; r < 4; ++r)
                    mk_nxt[r] = inputs[(size_t)(brow0 + r) * TT + tn];
            }

            // ---- h-part MFMAs ----
#pragma unroll
            for (int kt = 0; kt < 8; ++kt)
#pragma unroll
                for (int g = 0; g < 4; ++g)
                    acc[g] = __builtin_amdgcn_mfma_f32_16x16x32_bf16(hf[kt], wfrag[g][kt + 4], acc[g], 0, 0, 0);
        } else {
            // s==0: h=0; just prefetch next x + masks
#pragma unroll
            for (int kt = 0; kt < 4; ++kt)
                xf[kt] = *(const short8*)(xrow + (size_t)tn * EMBED + kt * 32 + 8 * lhi);
#pragma unroll
            for (int r = 0; r < 4; ++r)
                mk_nxt[r] = inputs[(size_t)(brow0 + r) * TT + tn];
        }

        // ---- gates (wave-local) ----
        unsigned hv16[4];
#pragma unroll
        for (int r = 0; r < 4; ++r) {
            float zi = acc[0][r];
            float zf = acc[1][r];
            float zg = acc[2][r];
            float zo = acc[3][r];
            float cn = sigf(zf) * c_st[r] + sigf(zi) * ftanh(zg);
            float hn = sigf(zo) * ftanh(cn);
            if (mk_cur[r] > 0) { c_st[r] = cn; h_st[r] = hn; }
            __hip_bfloat16 hbf = __float2bfloat16(h_st[r]);
            hv16[r] = (unsigned)(*(unsigned short*)&hbf);
        }
#pragma unroll
        for (int r = 0; r < 4; ++r) mk_cur[r] = mk_nxt[r];

        // ---- publish h(s+1): stores + ack, then per-wave flag ----
        {
            const short* sb = hbufs + (size_t)(dir * 2 + ((s + 1) & 1)) * BB * HID
                            + (size_t)brow0 * HID + jg * 32 + jch * 16 + l15;
            if constexpr (FAST) {
                asm volatile(
                    "global_store_short %4, %0, off sc0\n\t"
                    "global_store_short %4, %1, off offset:512 sc0\n\t"
                    "global_store_short %4, %2, off offset:1024 sc0\n\t"
                    "global_store_short %4, %3, off offset:1536 sc0\n\t"
                    "s_waitcnt vmcnt(0)"
                    :: "v"(hv16[0]), "v"(hv16[1]), "v"(hv16[2]), "v"(hv16[3]), "v"(sb)
                    : "memory");
                if (lane == 0) {
                    int val = s + 1;
                    asm volatile("global_store_dword %0, %1, off sc0"
                                 :: "v"(myflag), "v"(val) : "memory");
                }
            } else {
                asm volatile(
                    "global_store_short %4, %0, off sc0 sc1\n\t"
                    "global_store_short %4, %1, off offset:512 sc0 sc1\n\t"
                    "global_store_short %4, %2, off offset:1024 sc0 sc1\n\t"
                    "global_store_short %4, %3, off offset:1536 sc0 sc1\n\t"
                    "s_waitcnt vmcnt(0)"
                    :: "v"(hv16[0]), "v"(hv16[1]), "v"(hv16[2]), "v"(hv16[3]), "v"(sb)
                    : "memory");
                if (lane == 0) {
                    int val = s + 1;
                    asm volatile("global_store_dword %0, %1, off sc0 sc1"
                                 :: "v"(myflag), "v"(val) : "memory");
                }
            }
        }
    }
}

__launch_bounds__(256, 1)
__global__ void lstm_kernel(const int* __restrict__ inputs,
                            const __hip_bfloat16* __restrict__ xhat,
                            const __hip_bfloat16* __restrict__ WUp,
                            const float* __restrict__ bp,
                            __hip_bfloat16* __restrict__ hbuf,
                            float* __restrict__ hfinal,
                            int* __restrict__ flags,
                            int* __restrict__ xcdtab) {
    const int bid = blockIdx.x;          // bid = jg*16 + dir*8 + bg  (jg-peers share bid%8)
    const int jg  = bid >> 4;
    const int dir = (bid >> 3) & 1;
    const int bg  = bid & 7;
    const int tid = threadIdx.x;
    const int wid = tid >> 6;            // wave 0..3
    const int lane = tid & 63;
    const int l15 = lane & 15, lhi = lane >> 4;
    const int jch = wid & 1;             // output col half within jg's 32
    const int mrow0 = bg * 32 + (wid >> 1) * 16;
    const int brow0 = mrow0 + 4 * lhi;

    // ---- preload weights: 4 gates x 12 k-tiles ----
    short8 wfrag[4][12];
    const short* wu = (const short*)WUp + (size_t)(dir * 8 + jg) * 4 * 32 * 384;
#pragma unroll
    for (int g = 0; g < 4; ++g)
#pragma unroll
        for (int kt = 0; kt < 12; ++kt)
            wfrag[g][kt] = *(const short8*)(wu + (size_t)(g * 32 + jch * 16 + l15) * 384 + kt * 32 + 8 * lhi);

    float bias[4];
#pragma unroll
    for (int g = 0; g < 4; ++g)
        bias[g] = bp[((dir * 8 + jg) * 4 + g) * 32 + jch * 16 + l15];

    // ---- XCD co-residency handshake (device scope, once) ----
    int myxcd;
    asm volatile("s_getreg_b32 %0, hwreg(HW_REG_XCC_ID)" : "=s"(myxcd));
    if (tid == 0) {
        int* mp = xcdtab + bid * 16;
        int pv = 0x100 | myxcd;
        asm volatile("global_store_dword %0, %1, off sc0 sc1" :: "v"(mp), "v"(pv) : "memory");
    }
    int fast;
    {
        const int l8 = lane & 7;
        int* pp = xcdtab + ((l8 * 16) + dir * 8 + bg) * 16;   // peer jg=l8 of my group
        int e, guard = 0;
        do {
            asm volatile("global_load_dword %0, %1, off sc0 sc1\n\t"
                         "s_waitcnt vmcnt(0)"
                         : "=v"(e) : "v"(pp) : "memory");
            if (++guard > HS_GUARD) break;                    // e stays 0 -> slow path
        } while (__any(e == 0));
        fast = (__all(e == (0x100 | myxcd))) ? 1 : 0;
    }

    float c_st[4] = {0, 0, 0, 0};
    float h_st[4] = {0, 0, 0, 0};
    const short* xrow = (const short*)xhat + (size_t)(mrow0 + l15) * TT * EMBED;
    short* hbufs = (short*)hbuf;

    if (fast)
        lstm_loop<true>(dir, jg, bg, wid, lane, inputs, xrow, hbufs, flags,
                        wfrag, bias, c_st, h_st, brow0, mrow0, l15, lhi, jch);
    else
        lstm_loop<false>(dir, jg, bg, wid, lane, inputs, xrow, hbufs, flags,
                         wfrag, bias, c_st, h_st, brow0, mrow0, l15, lhi, jch);

#pragma unroll
    for (int r = 0; r < 4; ++r)
        hfinal[((size_t)dir * BB + brow0 + r) * HID + jg * 32 + jch * 16 + l15] = h_st[r];
}

__global__ void epilogue_kernel(const int* __restrict__ input_end,
                                const float* __restrict__ hfinal,
                                const float* __restrict__ cls_W, const float* __restrict__ cls_b,
                                const float* __restrict__ ent_W, const float* __restrict__ ent_b,
                                float* __restrict__ out) {
    int b = blockIdx.x;
    int lane = threadIdx.x;   // 64 threads
    int ie = input_end[b];
    float pe0 = 0, pe1 = 0, pe2 = 0, pc = 0;
    for (int k = lane; k < 2 * HID; k += 64) {
        float bv, se;
        if (k < HID) {
            bv = hfinal[(size_t)b * HID + k];
            se = hfinal[(size_t)ie * HID + k];
        } else {
            bv = hfinal[(size_t)(BB + b) * HID + (k - HID)];
            se = hfinal[(size_t)(BB + ie) * HID + (k - HID)];
        }
        pe0 += bv * ent_W[k * 3 + 0];
        pe1 += bv * ent_W[k * 3 + 1];
        pe2 += bv * ent_W[k * 3 + 2];
        pc  += se * cls_W[k];
    }
    for (int off = 32; off; off >>= 1) {
        pe0 += __shfl_down(pe0, off);
        pe1 += __shfl_down(pe1, off);
        pe2 += __shfl_down(pe2, off);
        pc  += __shfl_down(pc, off);
    }
    if (lane == 0) {
        float l0 = pe0 + ent_b[0], l1 = pe1 + ent_b[1], l2 = pe2 + ent_b[2];
        float m = fmaxf(l0, fmaxf(l1, l2));
        float e0 = __expf(l0 - m), e1 = __expf(l1 - m), e2 = __expf(l2 - m);
        float ssum = e0 + e1 + e2;
        out[256 + b * 3 + 0] = e0 / ssum;
        out[256 + b * 3 + 1] = e1 / ssum;
        out[256 + b * 3 + 2] = e2 / ssum;
        float cl = pc + cls_b[0];
        out[b] = 1.f / (1.f + __expf(-cl));
    }
}

extern "C" void kernel_launch(void* const* d_in, const int* in_sizes, int n_in,
                              void* d_out, int out_size, void* d_ws, size_t ws_size,
                              hipStream_t stream) {
    const int*   inputs    = (const int*)d_in[0];
    const int*   input_end = (const int*)d_in[1];
    const float* embed     = (const float*)d_in[2];
    const float* Wf        = (const float*)d_in[3];
    const float* Uf        = (const float*)d_in[4];
    const float* bf        = (const float*)d_in[5];
    const float* Wb        = (const float*)d_in[6];
    const float* Ub        = (const float*)d_in[7];
    const float* bb        = (const float*)d_in[8];
    const float* cls_W     = (const float*)d_in[9];
    const float* cls_b     = (const float*)d_in[10];
    const float* ent_W     = (const float*)d_in[11];
    const float* ent_b     = (const float*)d_in[12];
    float* out = (float*)d_out;

    char* ws = (char*)d_ws;
    __hip_bfloat16* WUp    = (__hip_bfloat16*)(ws + OFF_WUP);
    float*          bp     = (float*)(ws + OFF_BP);
    __hip_bfloat16* xhat   = (__hip_bfloat16*)(ws + OFF_XHAT);
    __hip_bfloat16* hbuf   = (__hip_bfloat16*)(ws + OFF_HBUF);
    float*          hfinal = (float*)(ws + OFF_HFIN);
    int*            flags  = (int*)(ws + OFF_FLAGS);
    int*            xcdtab = (int*)(ws + OFF_XCD);

    // 1) writeback+invalidate every XCD L2 (stale-line hygiene for sc1 traffic)
    preclean_kernel<<<64, 64, 0, stream>>>();
    // 2) zero flags + xcdtab (contiguous, 139264 B = 34816 dwords) at MALL
    init_flags_kernel<<<136, 256, 0, stream>>>(flags);
    pack_kernel<<<3072, 256, 0, stream>>>(Wf, Uf, bf, Wb, Ub, bb, WUp, bp);
    gather_kernel<<<BB * TT / 2, 256, 0, stream>>>(inputs, embed, xhat);

    void* args[] = {(void*)&inputs, (void*)&xhat, (void*)&WUp, (void*)&bp,
                    (void*)&hbuf, (void*)&hfinal, (void*)&flags, (void*)&xcdtab};
    hipLaunchCooperativeKernel((void*)lstm_kernel, dim3(128), dim3(256), args, 0, stream);

    epilogue_kernel<<<BB, 64, 0, stream>>>(input_end, hfinal, cls_W, cls_b, ent_W, ent_b, out);
}

// Round 10
// 994.561 us; speedup vs baseline: 907.9626x; 1.1547x over previous
//
#include <hip/hip_runtime.h>
#include <hip/hip_bf16.h>
#include <hip/hip_cooperative_groups.h>

#define EMBED 128
#define HID   256
#define BB    256   // batch
#define TT    512   // time
#define G4    1024  // 4*HID

typedef __attribute__((ext_vector_type(8))) short short8;
typedef __attribute__((ext_vector_type(4))) float f32x4;

// ---- workspace layout (bytes) ----
#define OFF_WUP   0
#define SZ_WUP    (2*8*4*32*384*2)           // 1,572,864
#define OFF_BP    (OFF_WUP + SZ_WUP)
#define SZ_BP     (2*8*4*32*4)               // 4,096
#define OFF_XHAT  (OFF_BP + SZ_BP)
#define SZ_XHAT   ((size_t)BB*TT*EMBED*2)    // 33,554,432
#define OFF_HBUF  (OFF_XHAT + SZ_XHAT)
#define SZ_HBUF   (2*2*BB*HID*2)             // 524,288
#define OFF_HFIN  (OFF_HBUF + SZ_HBUF)
#define SZ_HFIN   (2*BB*HID*4)               // 524,288
#define OFF_FLAGS (OFF_HFIN + SZ_HFIN)
#define SZ_FLAGS  (2*8*8*4*64*4)             // 131,072 (512 wave-flags x 256B)
#define OFF_XCD   (OFF_FLAGS + SZ_FLAGS)
#define SZ_XCD    (128*16*4)                 // 8,192

#define SPIN_GUARD (1 << 14)
#define HS_GUARD   (1 << 20)

__global__ void pack_kernel(const float* __restrict__ Wf, const float* __restrict__ Uf,
                            const float* __restrict__ bf,
                            const float* __restrict__ Wb, const float* __restrict__ Ub,
                            const float* __restrict__ bb,
                            __hip_bfloat16* __restrict__ WUp, float* __restrict__ bp) {
    int flat = blockIdx.x * 256 + threadIdx.x;          // [0, 2*8*4*32*384)
    int k = flat % 384;
    int rest = flat / 384;                              // [dir][jg][gate][jc]
    int jc   = rest & 31;
    int gate = (rest >> 5) & 3;
    int jg   = (rest >> 7) & 7;
    int dir  = rest >> 10;
    int J = gate * 256 + jg * 32 + jc;
    const float* W = dir ? Wb : Wf;
    const float* U = dir ? Ub : Uf;
    float v = (k < 128) ? W[(size_t)k * G4 + J] : U[(size_t)(k - 128) * G4 + J];
    WUp[flat] = __float2bfloat16(v);
    if (k == 0) {
        const float* bias = dir ? bb : bf;
        bp[rest] = bias[J];
    }
}

__global__ void gather_kernel(const int* __restrict__ inputs, const float* __restrict__ embed,
                              __hip_bfloat16* __restrict__ xhat) {
    int row = blockIdx.x * 2 + (threadIdx.x >> 7);      // [0, B*T)
    int col = threadIdx.x & 127;
    int tok = inputs[row];
    xhat[(size_t)row * EMBED + col] = __float2bfloat16(embed[(size_t)tok * EMBED + col]);
}

// Writeback + invalidate the local XCD's L2 (64 blocks round-robin all 8 XCDs).
__global__ void preclean_kernel() {
    if (threadIdx.x == 0) {
        asm volatile("buffer_wbl2 sc1\n\t"
                     "s_waitcnt vmcnt(0)\n\t"
                     "buffer_inv sc1\n\t"
                     "s_waitcnt vmcnt(0)" ::: "memory");
    }
}

// Zero flags + xcdtab through the device-scope bypass path.
__global__ void init_flags_kernel(int* __restrict__ p) {
    int i = blockIdx.x * 256 + threadIdx.x;             // 34816 dwords
    int* q = p + i;
    unsigned z = 0;
    asm volatile("global_store_dword %0, %1, off sc0 sc1" :: "v"(q), "v"(z) : "memory");
}

// Fast reciprocal (v_rcp_f32, ~1ulp) -- avoids full-precision fdiv expansion.
__device__ __forceinline__ float frcp(float x) {
    float r;
    asm("v_rcp_f32 %0, %1" : "=v"(r) : "v"(x));
    return r;
}
__device__ __forceinline__ float sigf(float x)  { return frcp(1.f + __expf(-x)); }
__device__ __forceinline__ float ftanh(float x) { return 2.f * frcp(1.f + __expf(-2.f * x)) - 1.f; }

// FAST = all 8 jg-peer blocks of this (dir,bg) group share one XCD.
// Empirical gfx950 cache-bit model (R3/R5/R6/R7/R8/R9):
//   sc0 sc1 load  -> MALL, always fresh (~900cy)      [slow path]
//   sc0 load      -> may hit stale L1 forever         [NEVER use for polls]
//   sc1 load      -> bypass L1, may hit local L2      [fast path: polls + h]
//   sc0 store     -> write-through L1 into local L2   [fast path: h + flags]
template<bool FAST>
__device__ __forceinline__ void lstm_loop(
        int dir, int jg, int bg, int wid, int lane,
        const int* __restrict__ inputs, const short* __restrict__ xrow,
        short* __restrict__ hbufs, int* __restrict__ flags,
        const short8 (*wfrag)[12], const float* bias,
        float* c_st, float* h_st, int brow0, int mrow0, int l15, int lhi, int jch) {

    const int rh = wid >> 1;                 // row half of this wave
    int* myflag = flags + ((((dir * 8 + jg) * 8 + bg) * 4) + wid) * 64;
    const int l16 = lane & 15;
    int* pollp = flags + ((((dir * 8 + (l16 >> 1)) * 8 + bg) * 4) + (2 * rh + (l16 & 1))) * 64;

    // ---- strength-reduced per-lane pointers (advance by +-const each step) ----
    const int   dstep = dir ? -1 : 1;
    const short* xptr = xrow + (size_t)(dir ? (TT - 1) : 0) * EMBED + 8 * lhi;
    const int*  mkp   = inputs + (size_t)brow0 * TT + (dir ? (TT - 1) : 0);
    const int*  mkp2  = mkp + 2 * TT;
    const short* hrd0 = hbufs + (size_t)(dir * 2) * BB * HID
                      + (size_t)(mrow0 + l15) * HID + 8 * lhi;          // parity 0 read base
    const short* hrd1 = hrd0 + BB * HID;                                 // parity 1 read base
    short* hwr0 = hbufs + (size_t)(dir * 2) * BB * HID
                + (size_t)brow0 * HID + jg * 32 + jch * 16 + l15;        // parity 0 write base
    short* hwr1 = hwr0 + BB * HID;                                       // parity 1 write base

    // x fragments + masks for step 0 (normal cached loads)
    short8 xf[4];
    int mk_cur[4], mk_nxt[4];
#pragma unroll
    for (int kt = 0; kt < 4; ++kt)
        xf[kt] = *(const short8*)(xptr + kt * 32);
    mk_cur[0] = mkp[0]; mk_cur[1] = mkp[TT]; mk_cur[2] = mkp2[0]; mk_cur[3] = mkp2[TT];
    xptr += dstep * EMBED; mkp += dstep; mkp2 += dstep;   // now at t(step 1)

    for (int s = 0; s < TT; ++s) {
        // ---- x-part of z (xf prefetched); bias folded into acc init ----
        f32x4 acc[4];
#pragma unroll
        for (int g = 0; g < 4; ++g) {
            acc[g][0] = bias[g]; acc[g][1] = bias[g]; acc[g][2] = bias[g]; acc[g][3] = bias[g];
        }
#pragma unroll
        for (int kt = 0; kt < 4; ++kt)
#pragma unroll
            for (int g = 0; g < 4; ++g)
                acc[g] = __builtin_amdgcn_mfma_f32_16x16x32_bf16(xf[kt], wfrag[g][kt], acc[g], 0, 0, 0);

        if (s != 0) {
            // ---- wait for h(s): poll 16 producer-wave flags ----
            {
                int fv, guard = 0;
                if constexpr (FAST) {
                    do {
                        asm volatile("global_load_dword %0, %1, off sc1\n\t"
                                     "s_waitcnt vmcnt(0)"
                                     : "=v"(fv) : "v"(pollp) : "memory");
                        if (++guard > SPIN_GUARD) break;
                    } while (__any(fv < s));
                } else {
                    do {
                        asm volatile("global_load_dword %0, %1, off sc0 sc1\n\t"
                                     "s_waitcnt vmcnt(0)"
                                     : "=v"(fv) : "v"(pollp) : "memory");
                        if (++guard > SPIN_GUARD) break;
                    } while (__any(fv < s));
                }
            }

            // ---- h fragments ----
            short8 hf[8];
            const short* hbase = (s & 1) ? hrd1 : hrd0;
            if constexpr (FAST) {
                asm volatile(
                    "global_load_dwordx4 %0, %8, off sc1\n\t"
                    "global_load_dwordx4 %1, %8, off offset:64 sc1\n\t"
                    "global_load_dwordx4 %2, %8, off offset:128 sc1\n\t"
                    "global_load_dwordx4 %3, %8, off offset:192 sc1\n\t"
                    "global_load_dwordx4 %4, %8, off offset:256 sc1\n\t"
                    "global_load_dwordx4 %5, %8, off offset:320 sc1\n\t"
                    "global_load_dwordx4 %6, %8, off offset:384 sc1\n\t"
                    "global_load_dwordx4 %7, %8, off offset:448 sc1\n\t"
                    "s_waitcnt vmcnt(0)"
                    : "=&v"(hf[0]), "=&v"(hf[1]), "=&v"(hf[2]), "=&v"(hf[3]),
                      "=&v"(hf[4]), "=&v"(hf[5]), "=&v"(hf[6]), "=&v"(hf[7])
                    : "v"(hbase) : "memory");
            } else {
                asm volatile(
                    "global_load_dwordx4 %0, %8, off sc0 sc1\n\t"
                    "global_load_dwordx4 %1, %8, off offset:64 sc0 sc1\n\t"
                    "global_load_dwordx4 %2, %8, off offset:128 sc0 sc1\n\t"
                    "global_load_dwordx4 %3, %8, off offset:192 sc0 sc1\n\t"
                    "global_load_dwordx4 %4, %8, off offset:256 sc0 sc1\n\t"
                    "global_load_dwordx4 %5, %8, off offset:320 sc0 sc1\n\t"
                    "global_load_dwordx4 %6, %8, off offset:384 sc0 sc1\n\t"
                    "global_load_dwordx4 %7, %8, off offset:448 sc0 sc1\n\t"
                    "s_waitcnt vmcnt(0)"
                    : "=&v"(hf[0]), "=&v"(hf[1]), "=&v"(hf[2]), "=&v"(hf[3]),
                      "=&v"(hf[4]), "=&v"(hf[5]), "=&v"(hf[6]), "=&v"(hf[7])
                    : "v"(hbase) : "memory");
            }
            __builtin_amdgcn_sched_barrier(0);

            // ---- prefetch x + next-step masks (hide under MFMA+gates) ----
            if (s + 1 < TT) {
#pragma unroll
                for (int kt = 0; kt < 4; ++kt)
                    xf[kt] = *(const short8*)(xptr + kt * 32);
                mk_nxt[0] = mkp[0]; mk_nxt[1] = mkp[TT];
                mk_nxt[2] = mkp2[0]; mk_nxt[3] = mkp2[TT];
                xptr += dstep * EMBED; mkp += dstep; mkp2 += dstep;
            }

            // ---- h-part MFMAs ----
#pragma unroll
            for (int kt = 0; kt < 8; ++kt)
#pragma unroll
                for (int g = 0; g < 4; ++g)
                    acc[g] = __builtin_amdgcn_mfma_f32_16x16x32_bf16(hf[kt], wfrag[g][kt + 4], acc[g], 0, 0, 0);
        } else {
            // s==0: h=0; just prefetch next x + masks
#pragma unroll
            for (int kt = 0; kt < 4; ++kt)
                xf[kt] = *(const short8*)(xptr + kt * 32);
            mk_nxt[0] = mkp[0]; mk_nxt[1] = mkp[TT];
            mk_nxt[2] = mkp2[0]; mk_nxt[3] = mkp2[TT];
            xptr += dstep * EMBED; mkp += dstep; mkp2 += dstep;
        }

        // ---- gates (wave-local, rcp-based) ----
        unsigned hv16[4];
#pragma unroll
        for (int r = 0; r < 4; ++r) {
            float zi = acc[0][r];
            float zf = acc[1][r];
            float zg = acc[2][r];
            float zo = acc[3][r];
            float cn = sigf(zf) * c_st[r] + sigf(zi) * ftanh(zg);
            float hn = sigf(zo) * ftanh(cn);
            if (mk_cur[r] > 0) { c_st[r] = cn; h_st[r] = hn; }
            __hip_bfloat16 hbf = __float2bfloat16(h_st[r]);
            hv16[r] = (unsigned)(*(unsigned short*)&hbf);
        }
#pragma unroll
        for (int r = 0; r < 4; ++r) mk_cur[r] = mk_nxt[r];

        // ---- publish h(s+1): stores + ack, then per-wave flag ----
        {
            const short* sb = ((s + 1) & 1) ? hwr1 : hwr0;
            if constexpr (FAST) {
                asm volatile(
                    "global_store_short %4, %0, off sc0\n\t"
                    "global_store_short %4, %1, off offset:512 sc0\n\t"
                    "global_store_short %4, %2, off offset:1024 sc0\n\t"
                    "global_store_short %4, %3, off offset:1536 sc0\n\t"
                    "s_waitcnt vmcnt(0)"
                    :: "v"(hv16[0]), "v"(hv16[1]), "v"(hv16[2]), "v"(hv16[3]), "v"(sb)
                    : "memory");
                if (lane == 0) {
                    int val = s + 1;
                    asm volatile("global_store_dword %0, %1, off sc0"
                                 :: "v"(myflag), "v"(val) : "memory");
                }
            } else {
                asm volatile(
                    "global_store_short %4, %0, off sc0 sc1\n\t"
                    "global_store_short %4, %1, off offset:512 sc0 sc1\n\t"
                    "global_store_short %4, %2, off offset:1024 sc0 sc1\n\t"
                    "global_store_short %4, %3, off offset:1536 sc0 sc1\n\t"
                    "s_waitcnt vmcnt(0)"
                    :: "v"(hv16[0]), "v"(hv16[1]), "v"(hv16[2]), "v"(hv16[3]), "v"(sb)
                    : "memory");
                if (lane == 0) {
                    int val = s + 1;
                    asm volatile("global_store_dword %0, %1, off sc0 sc1"
                                 :: "v"(myflag), "v"(val) : "memory");
                }
            }
        }
    }
}

__launch_bounds__(256, 1)
__global__ void lstm_kernel(const int* __restrict__ inputs,
                            const __hip_bfloat16* __restrict__ xhat,
                            const __hip_bfloat16* __restrict__ WUp,
                            const float* __restrict__ bp,
                            __hip_bfloat16* __restrict__ hbuf,
                            float* __restrict__ hfinal,
                            int* __restrict__ flags,
                            int* __restrict__ xcdtab) {
    const int bid = blockIdx.x;          // bid = jg*16 + dir*8 + bg  (jg-peers share bid%8)
    const int jg  = bid >> 4;
    const int dir = (bid >> 3) & 1;
    const int bg  = bid & 7;
    const int tid = threadIdx.x;
    const int wid = tid >> 6;            // wave 0..3
    const int lane = tid & 63;
    const int l15 = lane & 15, lhi = lane >> 4;
    const int jch = wid & 1;             // output col half within jg's 32
    const int mrow0 = bg * 32 + (wid >> 1) * 16;
    const int brow0 = mrow0 + 4 * lhi;

    // ---- preload weights: 4 gates x 12 k-tiles ----
    short8 wfrag[4][12];
    const short* wu = (const short*)WUp + (size_t)(dir * 8 + jg) * 4 * 32 * 384;
#pragma unroll
    for (int g = 0; g < 4; ++g)
#pragma unroll
        for (int kt = 0; kt < 12; ++kt)
            wfrag[g][kt] = *(const short8*)(wu + (size_t)(g * 32 + jch * 16 + l15) * 384 + kt * 32 + 8 * lhi);

    float bias[4];
#pragma unroll
    for (int g = 0; g < 4; ++g)
        bias[g] = bp[((dir * 8 + jg) * 4 + g) * 32 + jch * 16 + l15];

    // ---- XCD co-residency handshake (device scope, once) ----
    int myxcd;
    asm volatile("s_getreg_b32 %0, hwreg(HW_REG_XCC_ID)" : "=s"(myxcd));
    if (tid == 0) {
        int* mp = xcdtab + bid * 16;
        int pv = 0x100 | myxcd;
        asm volatile("global_store_dword %0, %1, off sc0 sc1" :: "v"(mp), "v"(pv) : "memory");
    }
    int fast;
    {
        const int l8 = lane & 7;
        int* pp = xcdtab + ((l8 * 16) + dir * 8 + bg) * 16;   // peer jg=l8 of my group
        int e, guard = 0;
        do {
            asm volatile("global_load_dword %0, %1, off sc0 sc1\n\t"
                         "s_waitcnt vmcnt(0)"
                         : "=v"(e) : "v"(pp) : "memory");
            if (++guard > HS_GUARD) break;                    // e stays 0 -> slow path
        } while (__any(e == 0));
        fast = (__all(e == (0x100 | myxcd))) ? 1 : 0;
    }

    float c_st[4] = {0, 0, 0, 0};
    float h_st[4] = {0, 0, 0, 0};
    const short* xrow = (const short*)xhat + (size_t)(mrow0 + l15) * TT * EMBED;
    short* hbufs = (short*)hbuf;

    if (fast)
        lstm_loop<true>(dir, jg, bg, wid, lane, inputs, xrow, hbufs, flags,
                        wfrag, bias, c_st, h_st, brow0, mrow0, l15, lhi, jch);
    else
        lstm_loop<false>(dir, jg, bg, wid, lane, inputs, xrow, hbufs, flags,
                         wfrag, bias, c_st, h_st, brow0, mrow0, l15, lhi, jch);

#pragma unroll
    for (int r = 0; r < 4; ++r)
        hfinal[((size_t)dir * BB + brow0 + r) * HID + jg * 32 + jch * 16 + l15] = h_st[r];
}

__global__ void epilogue_kernel(const int* __restrict__ input_end,
                                const float* __restrict__ hfinal,
                                const float* __restrict__ cls_W, const float* __restrict__ cls_b,
                                const float* __restrict__ ent_W, const float* __restrict__ ent_b,
                                float* __restrict__ out) {
    int b = blockIdx.x;
    int lane = threadIdx.x;   // 64 threads
    int ie = input_end[b];
    float pe0 = 0, pe1 = 0, pe2 = 0, pc = 0;
    for (int k = lane; k < 2 * HID; k += 64) {
        float bv, se;
        if (k < HID) {
            bv = hfinal[(size_t)b * HID + k];
            se = hfinal[(size_t)ie * HID + k];
        } else {
            bv = hfinal[(size_t)(BB + b) * HID + (k - HID)];
            se = hfinal[(size_t)(BB + ie) * HID + (k - HID)];
        }
        pe0 += bv * ent_W[k * 3 + 0];
        pe1 += bv * ent_W[k * 3 + 1];
        pe2 += bv * ent_W[k * 3 + 2];
        pc  += se * cls_W[k];
    }
    for (int off = 32; off; off >>= 1) {
        pe0 += __shfl_down(pe0, off);
        pe1 += __shfl_down(pe1, off);
        pe2 += __shfl_down(pe2, off);
        pc  += __shfl_down(pc, off);
    }
    if (lane == 0) {
        float l0 = pe0 + ent_b[0], l1 = pe1 + ent_b[1], l2 = pe2 + ent_b[2];
        float m = fmaxf(l0, fmaxf(l1, l2));
        float e0 = __expf(l0 - m), e1 = __expf(l1 - m), e2 = __expf(l2 - m);
        float ssum = e0 + e1 + e2;
        out[256 + b * 3 + 0] = e0 / ssum;
        out[256 + b * 3 + 1] = e1 / ssum;
        out[256 + b * 3 + 2] = e2 / ssum;
        float cl = pc + cls_b[0];
        out[b] = 1.f / (1.f + __expf(-cl));
    }
}

extern "C" void kernel_launch(void* const* d_in, const int* in_sizes, int n_in,
                              void* d_out, int out_size, void* d_ws, size_t ws_size,
                              hipStream_t stream) {
    const int*   inputs    = (const int*)d_in[0];
    const int*   input_end = (const int*)d_in[1];
    const float* embed     = (const float*)d_in[2];
    const float* Wf        = (const float*)d_in[3];
    const float* Uf        = (const float*)d_in[4];
    const float* bf        = (const float*)d_in[5];
    const float* Wb        = (const float*)d_in[6];
    const float* Ub        = (const float*)d_in[7];
    const float* bb        = (const float*)d_in[8];
    const float* cls_W     = (const float*)d_in[9];
    const float* cls_b     = (const float*)d_in[10];
    const float* ent_W     = (const float*)d_in[11];
    const float* ent_b     = (const float*)d_in[12];
    float* out = (float*)d_out;

    char* ws = (char*)d_ws;
    __hip_bfloat16* WUp    = (__hip_bfloat16*)(ws + OFF_WUP);
    float*          bp     = (float*)(ws + OFF_BP);
    __hip_bfloat16* xhat   = (__hip_bfloat16*)(ws + OFF_XHAT);
    __hip_bfloat16* hbuf   = (__hip_bfloat16*)(ws + OFF_HBUF);
    float*          hfinal = (float*)(ws + OFF_HFIN);
    int*            flags  = (int*)(ws + OFF_FLAGS);
    int*            xcdtab = (int*)(ws + OFF_XCD);

    // 1) writeback+invalidate every XCD L2 (stale-line hygiene for sc1 traffic)
    preclean_kernel<<<64, 64, 0, stream>>>();
    // 2) zero flags + xcdtab (contiguous, 139264 B = 34816 dwords) at MALL
    init_flags_kernel<<<136, 256, 0, stream>>>(flags);
    pack_kernel<<<3072, 256, 0, stream>>>(Wf, Uf, bf, Wb, Ub, bb, WUp, bp);
    gather_kernel<<<BB * TT / 2, 256, 0, stream>>>(inputs, embed, xhat);

    void* args[] = {(void*)&inputs, (void*)&xhat, (void*)&WUp, (void*)&bp,
                    (void*)&hbuf, (void*)&hfinal, (void*)&flags, (void*)&xcdtab};
    hipLaunchCooperativeKernel((void*)lstm_kernel, dim3(128), dim3(256), args, 0, stream);

    epilogue_kernel<<<BB, 64, 0, stream>>>(input_end, hfinal, cls_W, cls_b, ent_W, ent_b, out);
}